// Round 1
// baseline (1840.594 us; speedup 1.0000x reference)
//
#include <hip/hip_runtime.h>
#include <math.h>

// Problem constants (from reference setup_inputs)
#define N_    32
#define C_    512
#define T_    2048
#define G_    4
#define K_    1024
#define DG    128
#define NTOK  (N_ * T_)          // 65536 tokens
#define NCT   ((size_t)N_ * C_ * T_)

// ---------------------------------------------------------------------------
// K0: per-code squared norms  cnorm[g*K + k] = sum_d cb[g,k,d]^2
// ---------------------------------------------------------------------------
__global__ void k_cnorm(const float* __restrict__ cb, float* __restrict__ cnorm) {
    int i = blockIdx.x * 256 + threadIdx.x;          // 0 .. G*K-1
    const float4* row = (const float4*)(cb + (size_t)i * DG);
    float s0 = 0.f, s1 = 0.f, s2 = 0.f, s3 = 0.f;
#pragma unroll
    for (int d = 0; d < DG / 4; ++d) {
        float4 v = row[d];
        s0 = fmaf(v.x, v.x, s0);
        s1 = fmaf(v.y, v.y, s1);
        s2 = fmaf(v.z, v.z, s2);
        s3 = fmaf(v.w, v.w, s3);
    }
    cnorm[i] = (s0 + s1) + (s2 + s3);
}

// ---------------------------------------------------------------------------
// K1: argmin over codes.  One thread = one (token, group).
//     dist_rel(k) = cnorm[k] - 2 * <x, c_k>   (xnorm constant -> irrelevant)
//     Codebook staged through LDS in 64-code (32 KiB) chunks; all lanes read
//     the same LDS address (broadcast, conflict-free).
// ---------------------------------------------------------------------------
__global__ void __launch_bounds__(256) k_argmin(const float* __restrict__ x,
                                                const float* __restrict__ cb,
                                                const float* __restrict__ cnorm,
                                                int* __restrict__ code_idx,
                                                float* __restrict__ counts) {
    __shared__ float lds[64 * DG];                   // 32 KiB
    const int g     = blockIdx.y;
    const int token = blockIdx.x * 256 + threadIdx.x;
    const int b     = token >> 11;                   // T = 2048
    const int t     = token & (T_ - 1);

    // Load this token's 128-dim group slice into registers.
    // x layout (N, C, T): element (b, g*128+d, t). Lane -> t : coalesced.
    const float* xp = x + ((size_t)b * C_ + g * DG) * T_ + t;
    float4 xr[DG / 4];
#pragma unroll
    for (int i = 0; i < DG / 4; ++i) {
        xr[i].x = xp[(size_t)(4 * i + 0) * T_];
        xr[i].y = xp[(size_t)(4 * i + 1) * T_];
        xr[i].z = xp[(size_t)(4 * i + 2) * T_];
        xr[i].w = xp[(size_t)(4 * i + 3) * T_];
    }

    float best  = 3.4e38f;
    int   bestk = 0;
    const float* cng = cnorm + g * K_;

    for (int k0 = 0; k0 < K_; k0 += 64) {
        __syncthreads();
        {   // stage 64 codes (contiguous 32 KiB of the codebook) into LDS
            const float4* src = (const float4*)(cb + ((size_t)g * K_ + k0) * DG);
            float4*       dst = (float4*)lds;
#pragma unroll
            for (int i = 0; i < 8; ++i)
                dst[threadIdx.x + 256 * i] = src[threadIdx.x + 256 * i];
        }
        __syncthreads();

#pragma unroll 2
        for (int kk = 0; kk < 64; ++kk) {
            const float4* crow = (const float4*)&lds[kk * DG];
            float a0 = 0.f, a1 = 0.f, a2 = 0.f, a3 = 0.f;
#pragma unroll
            for (int d = 0; d < DG / 4; ++d) {
                float4 c4 = crow[d];                 // broadcast LDS read
                a0 = fmaf(xr[d].x, c4.x, a0);
                a1 = fmaf(xr[d].y, c4.y, a1);
                a2 = fmaf(xr[d].z, c4.z, a2);
                a3 = fmaf(xr[d].w, c4.w, a3);
            }
            float dot  = (a0 + a1) + (a2 + a3);
            float dist = fmaf(-2.f, dot, cng[k0 + kk]);
            if (dist < best) { best = dist; bestk = k0 + kk; }  // first-min ties
        }
    }

    code_idx[(size_t)g * NTOK + token] = bestk;
    atomicAdd(&counts[g * K_ + bestk], 1.0f);
}

// ---------------------------------------------------------------------------
// K2: dequantize + write out (N,C,T) + loss partial sums.
//     One thread = one token; gathers code rows as float4 (L2-resident).
// ---------------------------------------------------------------------------
__global__ void __launch_bounds__(256) k_dequant(const float* __restrict__ x,
                                                 const float* __restrict__ cb,
                                                 const int* __restrict__ code_idx,
                                                 float* __restrict__ out,
                                                 float* __restrict__ loss_acc) {
    const int token = blockIdx.x * 256 + threadIdx.x;
    const int b     = token >> 11;
    const int t     = token & (T_ - 1);
    const size_t base = (size_t)b * C_ * T_ + t;

    float lsum = 0.f;
#pragma unroll
    for (int g = 0; g < G_; ++g) {
        const int idx = code_idx[(size_t)g * NTOK + token];
        const float4* row = (const float4*)(cb + ((size_t)g * K_ + idx) * DG);
        for (int d4 = 0; d4 < DG / 4; ++d4) {
            float4 v = row[d4];                      // 16B gather, L2-resident
            const int c = g * DG + d4 * 4;
            float x0 = x[base + (size_t)(c + 0) * T_];
            float x1 = x[base + (size_t)(c + 1) * T_];
            float x2 = x[base + (size_t)(c + 2) * T_];
            float x3 = x[base + (size_t)(c + 3) * T_];
            out[base + (size_t)(c + 0) * T_] = v.x;
            out[base + (size_t)(c + 1) * T_] = v.y;
            out[base + (size_t)(c + 2) * T_] = v.z;
            out[base + (size_t)(c + 3) * T_] = v.w;
            float d0 = v.x - x0, d1 = v.y - x1, d2 = v.z - x2, d3 = v.w - x3;
            lsum += d0 * d0 + d1 * d1 + d2 * d2 + d3 * d3;
        }
    }
    // wave(64)-level reduction, one atomic per wave
#pragma unroll
    for (int off = 32; off >= 1; off >>= 1)
        lsum += __shfl_down(lsum, off, 64);
    if ((threadIdx.x & 63) == 0) atomicAdd(loss_acc, lsum);
}

// ---------------------------------------------------------------------------
// K3: finalize loss & perplexity scalars.
// ---------------------------------------------------------------------------
__global__ void k_final(const float* __restrict__ counts,
                        const float* __restrict__ loss_acc,
                        float* __restrict__ out_scalars) {
    const int w    = threadIdx.x >> 6;               // wave = group
    const int lane = threadIdx.x & 63;
    float s = 0.f;
    for (int j = lane; j < K_; j += 64) {
        float p = counts[w * K_ + j] * (1.0f / NTOK);
        s += p * logf(p + 1e-10f);
    }
#pragma unroll
    for (int off = 32; off >= 1; off >>= 1)
        s += __shfl_down(s, off, 64);
    __shared__ float sg[4];
    if (lane == 0) sg[w] = s;
    __syncthreads();
    if (threadIdx.x == 0) {
        float perp = 0.f;
#pragma unroll
        for (int g = 0; g < G_; ++g) perp += expf(-sg[g]);
        perp *= 0.25f;
        float loss = 1.25f * loss_acc[0] / (float)((size_t)NTOK * C_);
        out_scalars[0] = loss;
        out_scalars[1] = perp;
    }
}

// ---------------------------------------------------------------------------
extern "C" void kernel_launch(void* const* d_in, const int* in_sizes, int n_in,
                              void* d_out, int out_size, void* d_ws, size_t ws_size,
                              hipStream_t stream) {
    const float* x  = (const float*)d_in[0];
    const float* cb = (const float*)d_in[1];
    float* out = (float*)d_out;

    char*  ws       = (char*)d_ws;
    int*   code_idx = (int*)ws;                              // NTOK*G ints (1 MiB)
    float* cnorm    = (float*)(ws + (size_t)NTOK * G_ * 4);  // G*K floats
    float* counts   = cnorm + G_ * K_;                       // G*K floats
    float* loss_acc = counts + G_ * K_;                      // 1 float

    // ws is poisoned before every launch: zero the accumulators.
    hipMemsetAsync(counts, 0, (G_ * K_ + 1) * sizeof(float), stream);

    k_cnorm<<<G_ * K_ / 256, 256, 0, stream>>>(cb, cnorm);

    dim3 ga(NTOK / 256, G_);
    k_argmin<<<ga, 256, 0, stream>>>(x, cb, cnorm, code_idx, counts);

    k_dequant<<<NTOK / 256, 256, 0, stream>>>(x, cb, code_idx, out, loss_acc);

    k_final<<<1, 256, 0, stream>>>(counts, loss_acc, out + NCT);
}